// Round 12
// baseline (315.081 us; speedup 1.0000x reference)
//
#include <hip/hip_runtime.h>
#include <hip/hip_bf16.h>
#include <stdint.h>

typedef unsigned short u16;

#define Bdim 8
#define Ldim 2048
#define Ddim 1024
#define NH 16
#define HD 64
#define MTOK (Bdim*Ldim)   // 16384

typedef __bf16 bf16x8 __attribute__((ext_vector_type(8)));
typedef float  f32x4  __attribute__((ext_vector_type(4)));
typedef float  f32x16 __attribute__((ext_vector_type(16)));

#define AS1 __attribute__((address_space(1)))
#define AS3 __attribute__((address_space(3)))

__device__ __forceinline__ void gload_lds16(const void* g, void* l) {
  __builtin_amdgcn_global_load_lds((const AS1 void*)g, (AS3 void*)l, 16, 0, 0);
}

__device__ __forceinline__ u16 f2bf(float f) {
  uint32_t u = __builtin_bit_cast(uint32_t, f);
  u += 0x7fffu + ((u >> 16) & 1u);   // round-to-nearest-even
  return (u16)(u >> 16);
}
__device__ __forceinline__ uint32_t pkpair(float lo, float hi) {
  return (uint32_t)f2bf(lo) | ((uint32_t)f2bf(hi) << 16);
}

// ---------------- fp32 -> bf16 convert ---------------------------------------
__global__ __launch_bounds__(256) void conv_f32_bf16(const float* __restrict__ in,
                                                     u16* __restrict__ out, int n4) {
  int i = blockIdx.x * 256 + threadIdx.x;
  if (i < n4) {
    float4 v = ((const float4*)in)[i];
    uint32_t w0 = (uint32_t)f2bf(v.x) | ((uint32_t)f2bf(v.y) << 16);
    uint32_t w1 = (uint32_t)f2bf(v.z) | ((uint32_t)f2bf(v.w) << 16);
    ((uint2*)out)[i] = make_uint2(w0, w1);
  }
}

// ---------------- W[K][N] fp32 -> Wt[N][K] bf16 (tiled transpose) ------------
__global__ __launch_bounds__(256) void conv_transpose_w(const float* __restrict__ W,
                                                        u16* __restrict__ Wt) {
  __shared__ float t[32][33];
  int tx = threadIdx.x & 31, ty = threadIdx.x >> 5;
  int k0 = blockIdx.x * 32, n0 = blockIdx.y * 32;
  #pragma unroll
  for (int i = 0; i < 32; i += 8)
    t[ty + i][tx] = W[(size_t)(k0 + ty + i) * Ddim + n0 + tx];
  __syncthreads();
  #pragma unroll
  for (int i = 0; i < 32; i += 8)
    Wt[(size_t)(n0 + ty + i) * Ddim + k0 + tx] = f2bf(t[tx][ty + i]);
}

// ---------------- 128x256 GEMM, 4 waves, 3-buffer deep pipeline ---------------
// 256 thr = 4 waves (1Mx4N), per-wave 128x64 (acc[8][4]), BK=32.
// LDS 72KB = 3 buf x (A[128][32] + B[256][32]) -> 2 blocks/CU (144KB): one
// block's LDS/barrier window hides under the other's MFMA (m114). 3 buffers
// give a 2-tile stage->read distance (~2500cyc >> 900 HBM) with counted
// vmcnt(12) and zero overwrite races (buf t+2 last read at tile t-1).
// Swizzle (64B rows): phys 16B-blk = fh ^ ((row>>1)&3), both-sides.
// ROUND-12 FIX: FUSED=0 epilogue Cf row stride was 132 < 256-col tile ->
// row aliasing corrupted the O-projection. Stride now 264 (66KB <= 72KB).
template <int FUSED>
__global__ __launch_bounds__(256, 2) void gemmT(const u16* __restrict__ A,
                                                const u16* __restrict__ Bt,
                                                const float* __restrict__ b0p,
                                                const float* __restrict__ b1p,
                                                const float* __restrict__ b2p,
                                                void* __restrict__ o0,
                                                void* __restrict__ o1,
                                                void* __restrict__ o2) {
  __shared__ alignas(16) u16 LP[36864];            // 72 KB, 3 x 12288 u16
  const int tid = threadIdx.x;
  const int wid = tid >> 6, lane = tid & 63;
  const int wc = wid;                               // 1x4 wave grid
  const int fr = lane & 15, fh = lane >> 4;
  constexpr int NTN = FUSED ? 12 : 4;

  // XCD-aware: 8 mt fast, nt mid, mt-chunk slow (A-set 2MB + B-panels in L2)
  const int bid = blockIdx.x;
  const int xcd = bid & 7, idx = bid >> 3;
  const int mt8 = idx & 7, rest = idx >> 3;
  const int nt = rest % NTN, chunk = rest / NTN;
  const int m0 = (xcd * 16 + chunk * 8 + mt8) * 128;
  const int n0g = nt * 256;

  // ds_read: logical 16B-block fh of a 64B row at phys fh^((row>>1)&3)
  const int cks = (fh ^ ((fr >> 1) & 3)) * 8;
  // staging: thread -> row tid>>2 (A; B rows +g*64), phys blk tid&3,
  // source block pre-swizzled with the same key
  const int srow = tid >> 2;
  const int sblk = (tid & 3) ^ ((srow >> 1) & 3);
  const u16* aS = A  + (size_t)(m0  + srow) * 1024 + sblk * 8;
  const u16* bS = Bt + (size_t)(n0g + srow) * 1024 + sblk * 8;

  // stage tile T into buffer B_: A 2 gloads (rows 0-63,64-127), B 4 gloads
#define STG(T, B_) do {                                                        \
    u16* d_ = (u16*)LP + (B_) * 12288 + (wid << 9);                            \
    const u16* a_ = aS + (size_t)(T) * 32;                                     \
    const u16* b_ = bS + (size_t)(T) * 32;                                     \
    gload_lds16(a_,          d_);                                              \
    gload_lds16(a_ + 65536,  d_ + 2048);                                       \
    gload_lds16(b_,          d_ + 4096);                                       \
    gload_lds16(b_ + 65536,  d_ + 6144);                                       \
    gload_lds16(b_ + 131072, d_ + 8192);                                       \
    gload_lds16(b_ + 196608, d_ + 10240);                                      \
  } while (0)
#define BAR() do { asm volatile("" ::: "memory");                              \
                   __builtin_amdgcn_s_barrier();                               \
                   asm volatile("" ::: "memory"); } while (0)

  f32x4 acc[8][4] = {};

#define COMPUTE(B_) do {                                                       \
    const u16* la_ = LP + (B_) * 12288;                                        \
    const u16* lb_ = la_ + 4096;                                               \
    bf16x8 bf_[4], af_[8];                                                     \
    _Pragma("unroll")                                                          \
    for (int n_ = 0; n_ < 4; ++n_)                                             \
      bf_[n_] = *(const bf16x8*)(lb_ + (wc * 64 + n_ * 16 + fr) * 32 + cks);   \
    _Pragma("unroll")                                                          \
    for (int m_ = 0; m_ < 8; ++m_)                                             \
      af_[m_] = *(const bf16x8*)(la_ + (m_ * 16 + fr) * 32 + cks);             \
    __builtin_amdgcn_s_setprio(1);                                             \
    _Pragma("unroll")                                                          \
    for (int m_ = 0; m_ < 8; ++m_)                                             \
      _Pragma("unroll")                                                        \
      for (int n_ = 0; n_ < 4; ++n_)                                           \
        acc[m_][n_] = __builtin_amdgcn_mfma_f32_16x16x32_bf16(                 \
            af_[m_], bf_[n_], acc[m_][n_], 0, 0, 0);                           \
    __builtin_amdgcn_s_setprio(0);                                             \
  } while (0)

  STG(0, 0);
  STG(1, 1);
  #pragma unroll 1
  for (int t = 0; t < 32; ++t) {
    const int b = t % 3;
    BAR();                                // all waves done reading buf (t-1)%3
    if (t < 30) STG(t + 2, (t + 2) % 3);  // prefetch 2 tiles ahead
    if (t < 30)       { asm volatile("s_waitcnt vmcnt(12)" ::: "memory"); }
    else if (t == 30) { asm volatile("s_waitcnt vmcnt(6)"  ::: "memory"); }
    else              { asm volatile("s_waitcnt vmcnt(0)"  ::: "memory"); }
    BAR();                                // tile t visible to all waves
    COMPUTE(b);
  }
  __syncthreads();                        // LDS reuse below

  if (FUSED) {
    const int which = nt >> 2;                    // 0 Q, 1 K, 2 V
    const int n0l = (nt & 3) * 256;
    const float* bias = which == 0 ? b0p : which == 1 ? b1p : b2p;
    u16* Out = (u16*)(which == 0 ? o0 : which == 1 ? o1 : o2);
    u16* Ct = LP;                                 // [64][264] u16 = 33.8KB
    #pragma unroll 1
    for (int h = 0; h < 2; ++h) {                 // row halves (64 rows)
      if (h) __syncthreads();
      #pragma unroll
      for (int n = 0; n < 4; ++n) {
        float bvv = bias[n0l + wc * 64 + n * 16 + fr];
        #pragma unroll
        for (int m = 0; m < 4; ++m)
          #pragma unroll
          for (int r = 0; r < 4; ++r)
            Ct[(m * 16 + fh * 4 + r) * 264 + wc * 64 + n * 16 + fr] =
                f2bf(acc[h * 4 + m][n][r] + bvv);
      }
      __syncthreads();
      if (which != 2) {
        // 64 rows x 32 8-col chunks = 2048 units
        #pragma unroll
        for (int j = 0; j < 8; ++j) {
          int u = j * 256 + tid, lr = u >> 5, c8 = u & 31;
          uint4 v = *(const uint4*)(Ct + lr * 264 + c8 * 8);
          *(uint4*)(Out + (size_t)(m0 + h * 64 + lr) * Ddim + n0l + c8 * 8) = v;
        }
      } else {
        // V per-token transposed: gather 16 cols-of-16 -> one 32B store
        #pragma unroll
        for (int j = 0; j < 4; ++j) {
          int u = j * 256 + tid, lr = u >> 4, ii = u & 15;
          u16 tmp[16];
          #pragma unroll
          for (int jj = 0; jj < 16; ++jj)
            tmp[jj] = Ct[lr * 264 + ii + 16 * jj];
          u16* dst = Out + (size_t)(m0 + h * 64 + lr) * Ddim + ii * 64 + (n0l >> 4);
          *(uint4*)dst = *(uint4*)tmp;
          *(uint4*)(dst + 8) = *(uint4*)(tmp + 8);
        }
      }
    }
  } else {
    float* Cf = (float*)LP;                       // [64][264] f32 = 66KB
    float* Out = (float*)o0;
    #pragma unroll 1
    for (int h = 0; h < 2; ++h) {                 // row halves
      if (h) __syncthreads();
      #pragma unroll
      for (int n = 0; n < 4; ++n) {
        float bvv = b0p[n0g + wc * 64 + n * 16 + fr];
        #pragma unroll
        for (int m = 0; m < 4; ++m)
          #pragma unroll
          for (int r = 0; r < 4; ++r)
            Cf[(m * 16 + fh * 4 + r) * 264 + wc * 64 + n * 16 + fr] =
                acc[h * 4 + m][n][r] + bvv;
      }
      __syncthreads();
      // 64 rows x 64 float4 chunks = 4096 units
      #pragma unroll
      for (int j = 0; j < 16; ++j) {
        int u = j * 256 + tid, lr = u >> 6, c4 = u & 63;
        float4 v = *(const float4*)(Cf + lr * 264 + c4 * 4);
        *(float4*)(Out + (size_t)(m0 + h * 64 + lr) * Ddim + n0g + c4 * 4) = v;
      }
    }
  }
#undef STG
#undef BAR
#undef COMPUTE
}

// ---------------- per-token attention via MFMA (unchanged, verified) ---------
__global__ __launch_bounds__(256) void attn_mfma(const u16* __restrict__ Q,
                                                 const u16* __restrict__ Kb,
                                                 const u16* __restrict__ Vt,
                                                 u16* __restrict__ Y) {
  const int wid = threadIdx.x >> 6, lane = threadIdx.x & 63;
  const int tok = blockIdx.x * 4 + wid;
  const size_t base = (size_t)tok * Ddim;
  const int hi = lane >> 5, c31 = lane & 31;

  const bf16x8 kf0 = *(const bf16x8*)(Kb + base + (size_t)c31 * NH + hi * 8);
  const bf16x8 kf1 = *(const bf16x8*)(Kb + base + (size_t)(32 + c31) * NH + hi * 8);
  const bf16x8 qf0 = *(const bf16x8*)(Q  + base + (size_t)c31 * NH + hi * 8);
  const bf16x8 qf1 = *(const bf16x8*)(Q  + base + (size_t)(32 + c31) * NH + hi * 8);
  bf16x8 bv[4];
  #pragma unroll
  for (int c = 0; c < 4; ++c)
    bv[c] = *(const bf16x8*)(Vt + base + (size_t)(lane & 15) * HD + c * 16 + hi * 8);

  const f32x16 z = {};
  f32x16 s00 = __builtin_amdgcn_mfma_f32_32x32x16_bf16(kf0, qf0, z, 0, 0, 0);
  f32x16 s01 = __builtin_amdgcn_mfma_f32_32x32x16_bf16(kf0, qf1, z, 0, 0, 0);
  f32x16 s11 = __builtin_amdgcn_mfma_f32_32x32x16_bf16(kf1, qf1, z, 0, 0, 0);

  float a[16], b0[16], b1[16];
  float mA = -3e38f, mB = -3e38f;
  #pragma unroll
  for (int r = 0; r < 16; ++r) {
    const int kl = (r & 3) + 8 * (r >> 2) + 4 * hi;
    const bool keep = kl <= c31;
    float v00 = fmaf(s00[r], 0.25f, 1e-6f);
    float v01 = fmaf(s01[r], 0.25f, 1e-6f);
    float v11 = fmaf(s11[r], 0.25f, 1e-6f);
    a[r]  = keep ? v00 : -3e38f;
    b0[r] = v01;
    b1[r] = keep ? v11 : -3e38f;
    mA = fmaxf(mA, a[r]);
    mB = fmaxf(mB, fmaxf(b0[r], b1[r]));
  }
  mA = fmaxf(mA, __shfl_xor(mA, 32, 64));
  mB = fmaxf(mB, __shfl_xor(mB, 32, 64));
  float sA = 0.f, sB = 0.f;
  #pragma unroll
  for (int r = 0; r < 16; ++r) {
    a[r]  = __expf(a[r]  - mA);  sA += a[r];
    b0[r] = __expf(b0[r] - mB);
    b1[r] = __expf(b1[r] - mB);  sB += b0[r] + b1[r];
  }
  sA += __shfl_xor(sA, 32, 64);
  sB += __shfl_xor(sB, 32, 64);
  const float iA = __builtin_amdgcn_rcpf(sA);
  const float iB = __builtin_amdgcn_rcpf(sB);

  uint32_t pA[4][2], pB0[4][2], pB1[4][2];
  #pragma unroll
  for (int m = 0; m < 4; ++m)
    #pragma unroll
    for (int t = 0; t < 2; ++t) {
      pA [m][t] = pkpair(a [4*m+2*t] * iA, a [4*m+2*t+1] * iA);
      pB0[m][t] = pkpair(b0[4*m+2*t] * iB, b0[4*m+2*t+1] * iB);
      pB1[m][t] = pkpair(b1[4*m+2*t] * iB, b1[4*m+2*t+1] * iB);
    }

#define AFRAG(dst, src, cp) do {                                              \
    uint32_t k0_ = hi ? src[2*(cp)+1][0] : src[2*(cp)][0];                    \
    uint32_t k1_ = hi ? src[2*(cp)+1][1] : src[2*(cp)][1];                    \
    uint32_t s0_ = hi ? src[2*(cp)][0]   : src[2*(cp)+1][0];                  \
    uint32_t s1_ = hi ? src[2*(cp)][1]   : src[2*(cp)+1][1];                  \
    uint32_t r0_ = (uint32_t)__shfl_xor((int)s0_, 32, 64);                    \
    uint32_t r1_ = (uint32_t)__shfl_xor((int)s1_, 32, 64);                    \
    union { uint32_t w[4]; bf16x8 v; } u_;                                    \
    u_.w[0] = hi ? r0_ : k0_;  u_.w[1] = hi ? r1_ : k1_;                      \
    u_.w[2] = hi ? k0_ : r0_;  u_.w[3] = hi ? k1_ : r1_;                      \
    dst = u_.v;                                                               \
  } while (0)

  f32x16 y0 = {}, y1 = {};
  bf16x8 af;
  AFRAG(af, pA, 0);  y0 = __builtin_amdgcn_mfma_f32_32x32x16_bf16(af, bv[0], y0, 0, 0, 0);
  AFRAG(af, pA, 1);  y0 = __builtin_amdgcn_mfma_f32_32x32x16_bf16(af, bv[1], y0, 0, 0, 0);
  AFRAG(af, pB0, 0); y1 = __builtin_amdgcn_mfma_f32_32x32x16_bf16(af, bv[0], y1, 0, 0, 0);
  AFRAG(af, pB0, 1); y1 = __builtin_amdgcn_mfma_f32_32x32x16_bf16(af, bv[1], y1, 0, 0, 0);
  AFRAG(af, pB1, 0); y1 = __builtin_amdgcn_mfma_f32_32x32x16_bf16(af, bv[2], y1, 0, 0, 0);
  AFRAG(af, pB1, 1); y1 = __builtin_amdgcn_mfma_f32_32x32x16_bf16(af, bv[3], y1, 0, 0, 0);
#undef AFRAG

  if (c31 < 16) {
    #pragma unroll
    for (int r = 0; r < 16; ++r) {
      const int row = (r & 3) + 8 * (r >> 2) + 4 * hi;
      Y[base + (size_t)row * NH + c31]        = f2bf(y0[r]);
      Y[base + (size_t)(32 + row) * NH + c31] = f2bf(y1[r]);
    }
  }
}

// ---------------- launch ------------------------------------------------------
extern "C" void kernel_launch(void* const* d_in, const int* in_sizes, int n_in,
                              void* d_out, int out_size, void* d_ws, size_t ws_size,
                              hipStream_t stream) {
  const float* x  = (const float*)d_in[0];
  const float* Wq = (const float*)d_in[1];
  const float* bq = (const float*)d_in[2];
  const float* Wk = (const float*)d_in[3];
  const float* bk = (const float*)d_in[4];
  const float* Wv = (const float*)d_in[5];
  const float* bv = (const float*)d_in[6];
  const float* Wo = (const float*)d_in[7];
  const float* bo = (const float*)d_in[8];
  float* out = (float*)d_out;

  u16* xb = (u16*)d_ws;                          // [16384][1024]
  u16* Wt = xb + (size_t)MTOK * Ddim;            // 4 x [1024][1024] transposed (q,k,v,o)
  u16* Qb = Wt + 4ull * Ddim * Ddim;
  u16* Kb = Qb + (size_t)MTOK * Ddim;
  u16* Vb = Kb + (size_t)MTOK * Ddim;            // Vt (per-token [nh][hd])
  u16* Yb = xb;                                  // reuse xb after attention

  conv_f32_bf16<<<(MTOK * Ddim / 4 + 255) / 256, 256, 0, stream>>>(x, xb, MTOK * Ddim / 4);

  dim3 tg(Ddim / 32, Ddim / 32);
  conv_transpose_w<<<tg, 256, 0, stream>>>(Wq, Wt + 0ull * Ddim * Ddim);
  conv_transpose_w<<<tg, 256, 0, stream>>>(Wk, Wt + 1ull * Ddim * Ddim);
  conv_transpose_w<<<tg, 256, 0, stream>>>(Wv, Wt + 2ull * Ddim * Ddim);
  conv_transpose_w<<<tg, 256, 0, stream>>>(Wo, Wt + 3ull * Ddim * Ddim);

  // fused QKV: Bt = [Wq^T | Wk^T | Wv^T]; grid = 128 mt x 12 nt = 1536 blocks
  gemmT<1><<<dim3(1536), 256, 0, stream>>>(xb, Wt, bq, bk, bv, Qb, Kb, Vb);

  attn_mfma<<<MTOK / 4, 256, 0, stream>>>(Qb, Kb, Vb, Yb);

  // output projection: 128 mt x 4 nt = 512 blocks
  gemmT<0><<<dim3(512), 256, 0, stream>>>(Yb, Wt + 3ull * Ddim * Ddim,
                                          bo, bo, bo, out, out, out);
}

// Round 13
// 202.234 us; speedup vs baseline: 1.5580x; 1.5580x over previous
//
#include <hip/hip_runtime.h>
#include <hip/hip_bf16.h>
#include <stdint.h>

typedef unsigned short u16;

#define Bdim 8
#define Ldim 2048
#define Ddim 1024
#define NH 16
#define HD 64
#define MTOK (Bdim*Ldim)   // 16384

typedef __bf16 bf16x8 __attribute__((ext_vector_type(8)));
typedef float  f32x4  __attribute__((ext_vector_type(4)));
typedef float  f32x16 __attribute__((ext_vector_type(16)));

#define AS1 __attribute__((address_space(1)))
#define AS3 __attribute__((address_space(3)))

__device__ __forceinline__ void gload_lds16(const void* g, void* l) {
  __builtin_amdgcn_global_load_lds((const AS1 void*)g, (AS3 void*)l, 16, 0, 0);
}

__device__ __forceinline__ u16 f2bf(float f) {
  uint32_t u = __builtin_bit_cast(uint32_t, f);
  u += 0x7fffu + ((u >> 16) & 1u);   // round-to-nearest-even
  return (u16)(u >> 16);
}
__device__ __forceinline__ uint32_t pkpair(float lo, float hi) {
  return (uint32_t)f2bf(lo) | ((uint32_t)f2bf(hi) << 16);
}

// ---------------- fp32 -> bf16 convert ---------------------------------------
__global__ __launch_bounds__(256) void conv_f32_bf16(const float* __restrict__ in,
                                                     u16* __restrict__ out, int n4) {
  int i = blockIdx.x * 256 + threadIdx.x;
  if (i < n4) {
    float4 v = ((const float4*)in)[i];
    uint32_t w0 = (uint32_t)f2bf(v.x) | ((uint32_t)f2bf(v.y) << 16);
    uint32_t w1 = (uint32_t)f2bf(v.z) | ((uint32_t)f2bf(v.w) << 16);
    ((uint2*)out)[i] = make_uint2(w0, w1);
  }
}

// ---------------- all 4 weights: W[K][N] fp32 -> Wt[N][K] bf16 (one launch) --
__global__ __launch_bounds__(256) void conv_transpose_w4(const float* __restrict__ Wq,
                                                         const float* __restrict__ Wk,
                                                         const float* __restrict__ Wv,
                                                         const float* __restrict__ Wo,
                                                         u16* __restrict__ WtBase) {
  __shared__ float t[32][33];
  const int w = blockIdx.z;
  const float* W = w == 0 ? Wq : w == 1 ? Wk : w == 2 ? Wv : Wo;
  u16* Wt = WtBase + (size_t)w * Ddim * Ddim;
  int tx = threadIdx.x & 31, ty = threadIdx.x >> 5;
  int k0 = blockIdx.x * 32, n0 = blockIdx.y * 32;
  #pragma unroll
  for (int i = 0; i < 32; i += 8)
    t[ty + i][tx] = W[(size_t)(k0 + ty + i) * Ddim + n0 + tx];
  __syncthreads();
  #pragma unroll
  for (int i = 0; i < 32; i += 8)
    Wt[(size_t)(n0 + ty + i) * Ddim + k0 + tx] = f2bf(t[tx][ty + i]);
}

// ---------------- 256x256 4-slot pipelined GEMM (round-5 best-known) ---------
// 512 thr = 8 waves (2Mx4N), per-wave 128x64 (acc[8][4] in AGPRs). BK=64,
// double-buffered 128KB LDS. Per K-tile: 4 slots; slot p = {issue 2 stage
// loads (t+1), counted vmcnt (slots 1,3), s_barrier, ds_read frags for p+1,
// setprio MFMA cluster for p}. Fragment regs double-buffered.
// Stage order per tile: B0,B1 | B2,B3 | A0,A2 | A1,A3 (chunks = 64-row groups).
template <int FUSED>
__global__ __launch_bounds__(512, 2) void gemm256(const u16* __restrict__ A,
                                                  const u16* __restrict__ Bt,
                                                  const float* __restrict__ b0p,
                                                  const float* __restrict__ b1p,
                                                  const float* __restrict__ b2p,
                                                  void* __restrict__ o0,
                                                  void* __restrict__ o1,
                                                  void* __restrict__ o2) {
  __shared__ alignas(16) u16 LP[65536];           // 128 KB
  u16* LA = LP;                                    // A: [2 buf][256][64]
  u16* LB = LP + 32768;                            // B: [2 buf][256][64]

  const int tid = threadIdx.x;
  const int wid = tid >> 6, lane = tid & 63;
  const int wr = wid >> 2, wc = wid & 3;           // 2x4 wave grid
  const int fr = lane & 15, fh = lane >> 4;
  const int key = fr & 7;

  const int bid = blockIdx.x;
  const int xcd = bid & 7, idx = bid >> 3;
  const int mt = xcd * 8 + (idx & 7);
  const int nt = idx >> 3;
  const int m0 = mt * 256;
  const int n0g = nt * 256;

  const int srow = wid * 8 + (lane >> 3);
  const int scol = ((lane & 7) ^ (lane >> 3)) * 8; // pre-swizzled source col
  const u16* aG = A  + (size_t)(m0  + srow) * 1024 + scol;
  const u16* bG = Bt + (size_t)(n0g + srow) * 1024 + scol;
  const int ldsW = wid * 512;

#define STG(MAT, S_, TILE, BUF)                                                 \
  gload_lds16(((MAT) ? bG : aG) + (size_t)(TILE) * 64 + (size_t)(S_) * 65536,   \
              ((MAT) ? LB : LA) + (BUF) * 16384 + (S_) * 4096 + ldsW)

#define RD_AF(DST, BUF, KS, MH) do {                                            \
    const u16* base_ = LA + (BUF) * 16384;                                      \
    const int p_ = (((KS) * 4 + fh) ^ key) * 8;                                 \
    _Pragma("unroll")                                                           \
    for (int mm_ = 0; mm_ < 4; ++mm_)                                           \
      DST[mm_] = *(const bf16x8*)(base_ +                                       \
                   (wr * 128 + (MH) * 64 + mm_ * 16 + fr) * 64 + p_);           \
  } while (0)
#define RD_BF(DST, BUF, KS) do {                                                \
    const u16* base_ = LB + (BUF) * 16384;                                      \
    const int p_ = (((KS) * 4 + fh) ^ key) * 8;                                 \
    _Pragma("unroll")                                                           \
    for (int n_ = 0; n_ < 4; ++n_)                                              \
      DST[n_] = *(const bf16x8*)(base_ + (wc * 64 + n_ * 16 + fr) * 64 + p_);   \
  } while (0)
#define MFMA16(AF, BF, MH) do {                                                 \
    __builtin_amdgcn_s_setprio(1);                                              \
    _Pragma("unroll")                                                           \
    for (int mm_ = 0; mm_ < 4; ++mm_)                                           \
      _Pragma("unroll")                                                         \
      for (int n_ = 0; n_ < 4; ++n_)                                            \
        acc[(MH) * 4 + mm_][n_] = __builtin_amdgcn_mfma_f32_16x16x32_bf16(      \
            AF[mm_], BF[n_], acc[(MH) * 4 + mm_][n_], 0, 0, 0);                 \
    __builtin_amdgcn_s_setprio(0);                                              \
  } while (0)
#define WAITV(N) asm volatile("s_waitcnt vmcnt(" #N ")" ::: "memory")
#define BAR() __builtin_amdgcn_s_barrier()

  f32x4 acc[8][4] = {};
  bf16x8 afA[4], afB[4], bf0[4], bf1[4];

  // prologue: tile 0 -> buf 0 (order B0..B3, A0, A2, A1, A3)
  STG(1,0,0,0); STG(1,1,0,0); STG(1,2,0,0); STG(1,3,0,0);
  STG(0,0,0,0); STG(0,2,0,0); STG(0,1,0,0); STG(0,3,0,0);
  WAITV(2); BAR();                      // B*, A0, A2 of tile 0 resident
  RD_AF(afA, 0, 0, 0); RD_BF(bf0, 0, 0);  // F[0]^0

  #pragma unroll 1
  for (int t = 0; t < 15; ++t) {
    const int cur = t & 1, nxt = cur ^ 1;
    // slot0: MFMA F0; read F1 (ks1,mh0 + bf1); stage B0,B1(t+1)
    STG(1,0,t+1,nxt); STG(1,1,t+1,nxt);
    BAR();
    RD_AF(afB, cur, 1, 0); RD_BF(bf1, cur, 1);
    MFMA16(afA, bf0, 0);
    // slot1: MFMA F1; read F2 (ks0,mh1); stage B2,B3; vmcnt(4) retires A1,A3(t)
    STG(1,2,t+1,nxt); STG(1,3,t+1,nxt);
    WAITV(4); BAR();
    RD_AF(afA, cur, 0, 1);
    MFMA16(afB, bf1, 0);
    // slot2: MFMA F2; read F3 (ks1,mh1); stage A0,A2(t+1)
    STG(0,0,t+1,nxt); STG(0,2,t+1,nxt);
    BAR();
    RD_AF(afB, cur, 1, 1);
    MFMA16(afA, bf0, 1);
    // slot3: MFMA F3; read F0^{t+1}; stage A1,A3(t+1) first (counted wait)
    STG(0,1,t+1,nxt); STG(0,3,t+1,nxt);
    WAITV(2); BAR();
    RD_AF(afA, nxt, 0, 0); RD_BF(bf0, nxt, 0);
    MFMA16(afB, bf1, 1);
  }
  // epilogue tile 15 (buf 1): F0 already in afA/bf0
  RD_AF(afB, 1, 1, 0); RD_BF(bf1, 1, 1);
  MFMA16(afA, bf0, 0);
  WAITV(0); BAR();                      // A1,A3 of tile 15
  RD_AF(afA, 1, 0, 1);
  MFMA16(afB, bf1, 0);
  RD_AF(afB, 1, 1, 1);
  MFMA16(afA, bf0, 1);
  MFMA16(afB, bf1, 1);

  __syncthreads();                      // LDS reuse below (Ct overlaps LA/LB)

  if (FUSED) {
    const int which = nt >> 2;                    // 0 Q, 1 K, 2 V
    const int n0l = (nt & 3) * 256;
    const float* bias = which == 0 ? b0p : which == 1 ? b1p : b2p;
    u16* Out = (u16*)(which == 0 ? o0 : which == 1 ? o1 : o2);
    u16* Ct = LP;                                 // [4 regions][128][72] u16
    #pragma unroll 1
    for (int h = 0; h < 2; ++h) {
      if (h) __syncthreads();
      if (wr == h) {
        #pragma unroll
        for (int n = 0; n < 4; ++n) {
          float bvv = bias[n0l + wc * 64 + n * 16 + fr];
          #pragma unroll
          for (int m = 0; m < 8; ++m)
            #pragma unroll
            for (int r = 0; r < 4; ++r)
              Ct[wc * 9216 + (m * 16 + fh * 4 + r) * 72 + n * 16 + fr] =
                  f2bf(acc[m][n][r] + bvv);
        }
      }
      __syncthreads();
      if (which != 2) {
        #pragma unroll
        for (int j = 0; j < 8; ++j) {
          int r = j * 16 + (tid >> 5), c8 = tid & 31;
          uint4 v = *(const uint4*)(Ct + (c8 >> 3) * 9216 + r * 72 + (c8 & 7) * 8);
          *(uint4*)(Out + (size_t)(m0 + h * 128 + r) * Ddim + n0l + c8 * 8) = v;
        }
      } else {
        // V per-token transposed: Vt[i=d&15][k=d>>4]
        #pragma unroll
        for (int j = 0; j < 4; ++j) {
          int q = j * 512 + tid, r = q >> 4, i = q & 15;
          u16 tmp[16];
          #pragma unroll
          for (int jj = 0; jj < 16; ++jj) {
            int c = i + 16 * jj;
            tmp[jj] = Ct[(c >> 6) * 9216 + r * 72 + (c & 63)];
          }
          u16* dst = Out + (size_t)(m0 + h * 128 + r) * Ddim + i * 64 + (n0l >> 4);
          *(uint4*)dst = *(uint4*)tmp;
          *(uint4*)(dst + 8) = *(uint4*)(tmp + 8);
        }
      }
      __syncthreads();
    }
  } else {
    float* Cf = (float*)LP;                       // [2 regions][128][68] f32
    float* Out = (float*)o0;
    #pragma unroll 1
    for (int h = 0; h < 4; ++h) {
      if (h) __syncthreads();
      if (wr == (h >> 1) && (wc >> 1) == (h & 1)) {
        #pragma unroll
        for (int n = 0; n < 4; ++n) {
          float bvv = b0p[n0g + (h & 1) * 128 + (wc & 1) * 64 + n * 16 + fr];
          #pragma unroll
          for (int m = 0; m < 8; ++m)
            #pragma unroll
            for (int r = 0; r < 4; ++r)
              Cf[(wc & 1) * 8704 + (m * 16 + fh * 4 + r) * 68 + n * 16 + fr] =
                  acc[m][n][r] + bvv;
        }
      }
      __syncthreads();
      #pragma unroll
      for (int j = 0; j < 8; ++j) {
        int r = j * 16 + (tid >> 5), c4 = tid & 31;
        float4 v = *(const float4*)(Cf + (c4 >> 4) * 8704 + r * 68 + (c4 & 15) * 4);
        *(float4*)(Out + (size_t)(m0 + (h >> 1) * 128 + r) * Ddim +
                   n0g + (h & 1) * 128 + c4 * 4) = v;
      }
      __syncthreads();
    }
  }
#undef STG
#undef RD_AF
#undef RD_BF
#undef MFMA16
#undef WAITV
#undef BAR
}

// ---------------- per-token attention via MFMA (unchanged, verified) ---------
__global__ __launch_bounds__(256) void attn_mfma(const u16* __restrict__ Q,
                                                 const u16* __restrict__ Kb,
                                                 const u16* __restrict__ Vt,
                                                 u16* __restrict__ Y) {
  const int wid = threadIdx.x >> 6, lane = threadIdx.x & 63;
  const int tok = blockIdx.x * 4 + wid;
  const size_t base = (size_t)tok * Ddim;
  const int hi = lane >> 5, c31 = lane & 31;

  const bf16x8 kf0 = *(const bf16x8*)(Kb + base + (size_t)c31 * NH + hi * 8);
  const bf16x8 kf1 = *(const bf16x8*)(Kb + base + (size_t)(32 + c31) * NH + hi * 8);
  const bf16x8 qf0 = *(const bf16x8*)(Q  + base + (size_t)c31 * NH + hi * 8);
  const bf16x8 qf1 = *(const bf16x8*)(Q  + base + (size_t)(32 + c31) * NH + hi * 8);
  bf16x8 bv[4];
  #pragma unroll
  for (int c = 0; c < 4; ++c)
    bv[c] = *(const bf16x8*)(Vt + base + (size_t)(lane & 15) * HD + c * 16 + hi * 8);

  const f32x16 z = {};
  f32x16 s00 = __builtin_amdgcn_mfma_f32_32x32x16_bf16(kf0, qf0, z, 0, 0, 0);
  f32x16 s01 = __builtin_amdgcn_mfma_f32_32x32x16_bf16(kf0, qf1, z, 0, 0, 0);
  f32x16 s11 = __builtin_amdgcn_mfma_f32_32x32x16_bf16(kf1, qf1, z, 0, 0, 0);

  float a[16], b0[16], b1[16];
  float mA = -3e38f, mB = -3e38f;
  #pragma unroll
  for (int r = 0; r < 16; ++r) {
    const int kl = (r & 3) + 8 * (r >> 2) + 4 * hi;
    const bool keep = kl <= c31;
    float v00 = fmaf(s00[r], 0.25f, 1e-6f);
    float v01 = fmaf(s01[r], 0.25f, 1e-6f);
    float v11 = fmaf(s11[r], 0.25f, 1e-6f);
    a[r]  = keep ? v00 : -3e38f;
    b0[r] = v01;
    b1[r] = keep ? v11 : -3e38f;
    mA = fmaxf(mA, a[r]);
    mB = fmaxf(mB, fmaxf(b0[r], b1[r]));
  }
  mA = fmaxf(mA, __shfl_xor(mA, 32, 64));
  mB = fmaxf(mB, __shfl_xor(mB, 32, 64));
  float sA = 0.f, sB = 0.f;
  #pragma unroll
  for (int r = 0; r < 16; ++r) {
    a[r]  = __expf(a[r]  - mA);  sA += a[r];
    b0[r] = __expf(b0[r] - mB);
    b1[r] = __expf(b1[r] - mB);  sB += b0[r] + b1[r];
  }
  sA += __shfl_xor(sA, 32, 64);
  sB += __shfl_xor(sB, 32, 64);
  const float iA = __builtin_amdgcn_rcpf(sA);
  const float iB = __builtin_amdgcn_rcpf(sB);

  uint32_t pA[4][2], pB0[4][2], pB1[4][2];
  #pragma unroll
  for (int m = 0; m < 4; ++m)
    #pragma unroll
    for (int t = 0; t < 2; ++t) {
      pA [m][t] = pkpair(a [4*m+2*t] * iA, a [4*m+2*t+1] * iA);
      pB0[m][t] = pkpair(b0[4*m+2*t] * iB, b0[4*m+2*t+1] * iB);
      pB1[m][t] = pkpair(b1[4*m+2*t] * iB, b1[4*m+2*t+1] * iB);
    }

#define AFRAG(dst, src, cp) do {                                              \
    uint32_t k0_ = hi ? src[2*(cp)+1][0] : src[2*(cp)][0];                    \
    uint32_t k1_ = hi ? src[2*(cp)+1][1] : src[2*(cp)][1];                    \
    uint32_t s0_ = hi ? src[2*(cp)][0]   : src[2*(cp)+1][0];                  \
    uint32_t s1_ = hi ? src[2*(cp)][1]   : src[2*(cp)+1][1];                  \
    uint32_t r0_ = (uint32_t)__shfl_xor((int)s0_, 32, 64);                    \
    uint32_t r1_ = (uint32_t)__shfl_xor((int)s1_, 32, 64);                    \
    union { uint32_t w[4]; bf16x8 v; } u_;                                    \
    u_.w[0] = hi ? r0_ : k0_;  u_.w[1] = hi ? r1_ : k1_;                      \
    u_.w[2] = hi ? k0_ : r0_;  u_.w[3] = hi ? k1_ : r1_;                      \
    dst = u_.v;                                                               \
  } while (0)

  f32x16 y0 = {}, y1 = {};
  bf16x8 af;
  AFRAG(af, pA, 0);  y0 = __builtin_amdgcn_mfma_f32_32x32x16_bf16(af, bv[0], y0, 0, 0, 0);
  AFRAG(af, pA, 1);  y0 = __builtin_amdgcn_mfma_f32_32x32x16_bf16(af, bv[1], y0, 0, 0, 0);
  AFRAG(af, pB0, 0); y1 = __builtin_amdgcn_mfma_f32_32x32x16_bf16(af, bv[0], y1, 0, 0, 0);
  AFRAG(af, pB0, 1); y1 = __builtin_amdgcn_mfma_f32_32x32x16_bf16(af, bv[1], y1, 0, 0, 0);
  AFRAG(af, pB1, 0); y1 = __builtin_amdgcn_mfma_f32_32x32x16_bf16(af, bv[2], y1, 0, 0, 0);
  AFRAG(af, pB1, 1); y1 = __builtin_amdgcn_mfma_f32_32x32x16_bf16(af, bv[3], y1, 0, 0, 0);
#undef AFRAG

  if (c31 < 16) {
    #pragma unroll
    for (int r = 0; r < 16; ++r) {
      const int row = (r & 3) + 8 * (r >> 2) + 4 * hi;
      Y[base + (size_t)row * NH + c31]        = f2bf(y0[r]);
      Y[base + (size_t)(32 + row) * NH + c31] = f2bf(y1[r]);
    }
  }
}

// ---------------- launch ------------------------------------------------------
extern "C" void kernel_launch(void* const* d_in, const int* in_sizes, int n_in,
                              void* d_out, int out_size, void* d_ws, size_t ws_size,
                              hipStream_t stream) {
  const float* x  = (const float*)d_in[0];
  const float* Wq = (const float*)d_in[1];
  const float* bq = (const float*)d_in[2];
  const float* Wk = (const float*)d_in[3];
  const float* bk = (const float*)d_in[4];
  const float* Wv = (const float*)d_in[5];
  const float* bv = (const float*)d_in[6];
  const float* Wo = (const float*)d_in[7];
  const float* bo = (const float*)d_in[8];
  float* out = (float*)d_out;

  u16* xb = (u16*)d_ws;                          // [16384][1024]
  u16* Wt = xb + (size_t)MTOK * Ddim;            // 4 x [1024][1024] transposed (q,k,v,o)
  u16* Qb = Wt + 4ull * Ddim * Ddim;
  u16* Kb = Qb + (size_t)MTOK * Ddim;
  u16* Vb = Kb + (size_t)MTOK * Ddim;            // Vt (per-token [nh][hd])
  u16* Yb = xb;                                  // reuse xb after attention

  conv_f32_bf16<<<(MTOK * Ddim / 4 + 255) / 256, 256, 0, stream>>>(x, xb, MTOK * Ddim / 4);

  dim3 tg(Ddim / 32, Ddim / 32, 4);
  conv_transpose_w4<<<tg, 256, 0, stream>>>(Wq, Wk, Wv, Wo, Wt);

  // fused QKV: Bt = [Wq^T | Wk^T | Wv^T] (3072 rows); 64 mt x 12 nt = 768 blocks
  gemm256<1><<<dim3(768), 512, 0, stream>>>(xb, Wt, bq, bk, bv, Qb, Kb, Vb);

  attn_mfma<<<MTOK / 4, 256, 0, stream>>>(Qb, Kb, Vb, Yb);

  // output projection: 64 mt x 4 nt = 256 blocks
  gemm256<0><<<dim3(256), 512, 0, stream>>>(Yb, Wt + 3ull * Ddim * Ddim,
                                            bo, bo, bo, out, out, out);
}